// Round 1
// baseline (921.202 us; speedup 1.0000x reference)
//
#include <hip/hip_runtime.h>

// WL_DiffNet: B=64, N=512, MAX_NB=10, H=256, BOND_F=5, DEPTH=3
// Factored algorithm:
//   Hb2 = input_bond @ W2[256:261] + b2              (once; [32768,256])
//   per depth:
//     G = feats @ W2[0:256]                          ([32768,256], 4.3 GF)
//     nei[r] = sum_{k<nnb} relu(G[anei]+Hb2[bnei])   (gather, L2-resident)
//     feats' = relu(feats@W1[0:256] + nei@W1[256:512] + b1)   (8.6 GF)
//   out[b,h] = sum_n feats[b,n,h]
// Exact same math as reference (matmul linearity commutes with gather).

#define BB 64
#define NN 512
#define MAXNB 10
#define HH 256
#define BONDF 5
#define WLDEPTH 3
#define ROWS (BB*NN)   // 32768
#define TILE 32

__global__ __launch_bounds__(256) void hb2_kernel(const float* __restrict__ bond,
                                                  const float* __restrict__ W2,
                                                  const float* __restrict__ b2,
                                                  float* __restrict__ Hb2) {
    int row = blockIdx.x;
    int c = threadIdx.x;
    float s = b2[c];
    float bv[BONDF];
#pragma unroll
    for (int f = 0; f < BONDF; ++f) bv[f] = bond[row * BONDF + f];
#pragma unroll
    for (int f = 0; f < BONDF; ++f) s += bv[f] * W2[(HH + f) * HH + c];
    Hb2[(size_t)row * HH + c] = s;
}

// G = A[32768,256] @ W2a[256,256]; 32-row tile per block, 8 rows x 4 cols per thread
__global__ __launch_bounds__(256) void gemmA_kernel(const float* __restrict__ A,
                                                    const float* __restrict__ W2,
                                                    float* __restrict__ G) {
    __shared__ float As[TILE][HH];
    int base = blockIdx.x * TILE;
    const float4* A4 = (const float4*)(A + (size_t)base * HH);
    float4* As4 = (float4*)&As[0][0];
#pragma unroll
    for (int i = 0; i < 8; ++i) As4[threadIdx.x + i * 256] = A4[threadIdx.x + i * 256];
    __syncthreads();

    int c = threadIdx.x & 63;          // cols c, c+64, c+128, c+192
    int r0 = (threadIdx.x >> 6) * 8;   // 8 rows per thread
    float acc[8][4] = {};
    for (int k = 0; k < HH; k += 4) {
        float w[4][4];
#pragma unroll
        for (int kk = 0; kk < 4; ++kk)
#pragma unroll
            for (int j = 0; j < 4; ++j)
                w[kk][j] = W2[(size_t)(k + kk) * HH + c + 64 * j];
#pragma unroll
        for (int r = 0; r < 8; ++r) {
            float4 av = *(const float4*)&As[r0 + r][k];
            float a_[4] = {av.x, av.y, av.z, av.w};
#pragma unroll
            for (int kk = 0; kk < 4; ++kk)
#pragma unroll
                for (int j = 0; j < 4; ++j)
                    acc[r][j] += a_[kk] * w[kk][j];
        }
    }
#pragma unroll
    for (int r = 0; r < 8; ++r)
#pragma unroll
        for (int j = 0; j < 4; ++j)
            G[(size_t)(base + r0 + r) * HH + c + 64 * j] = acc[r][j];
}

// Phase 1: nei aggregation (gather G/Hb2 rows of own batch, relu, masked sum).
// Phase 2: feats' = relu(Fs@W1a + Ns@W1b + b1)
__global__ __launch_bounds__(256) void fuseB_kernel(const float* __restrict__ Fin,
                                                    const float* __restrict__ G,
                                                    const float* __restrict__ Hb2,
                                                    const int* __restrict__ agr,
                                                    const int* __restrict__ bgr,
                                                    const int* __restrict__ nnbp,
                                                    const float* __restrict__ W1,
                                                    const float* __restrict__ b1,
                                                    float* __restrict__ Fout) {
    __shared__ float Fs[TILE][HH];
    __shared__ float Ns[TILE][HH];
    int base = blockIdx.x * TILE;
    int brow = (base >> 9) << 9;   // batch row base (32 | 512, so block is batch-pure)

    const float4* F4 = (const float4*)(Fin + (size_t)base * HH);
    float4* Fs4 = (float4*)&Fs[0][0];
#pragma unroll
    for (int i = 0; i < 8; ++i) Fs4[threadIdx.x + i * 256] = F4[threadIdx.x + i * 256];

    // phase 1: thread owns column c for all 32 rows (indices are wave-uniform)
    int c = threadIdx.x;
    for (int r = 0; r < TILE; ++r) {
        int row = base + r;
        int nn = nnbp[row];
        float s = 0.f;
        for (int k = 0; k < nn; ++k) {
            int an = agr[(row * MAXNB + k) * 2 + 1];
            int bn = bgr[(row * MAXNB + k) * 2 + 1];
            float v = G[(size_t)(brow + an) * HH + c] + Hb2[(size_t)(brow + bn) * HH + c];
            s += fmaxf(v, 0.f);
        }
        Ns[r][c] = s;
    }
    __syncthreads();

    // phase 2
    int cc = threadIdx.x & 63;
    int r0 = (threadIdx.x >> 6) * 8;
    float acc[8][4] = {};
    for (int k = 0; k < HH; k += 4) {
        float w[4][4];
#pragma unroll
        for (int kk = 0; kk < 4; ++kk)
#pragma unroll
            for (int j = 0; j < 4; ++j)
                w[kk][j] = W1[(size_t)(k + kk) * HH + cc + 64 * j];
#pragma unroll
        for (int r = 0; r < 8; ++r) {
            float4 av = *(const float4*)&Fs[r0 + r][k];
            float a_[4] = {av.x, av.y, av.z, av.w};
#pragma unroll
            for (int kk = 0; kk < 4; ++kk)
#pragma unroll
                for (int j = 0; j < 4; ++j)
                    acc[r][j] += a_[kk] * w[kk][j];
        }
    }
    for (int k = 0; k < HH; k += 4) {
        float w[4][4];
#pragma unroll
        for (int kk = 0; kk < 4; ++kk)
#pragma unroll
            for (int j = 0; j < 4; ++j)
                w[kk][j] = W1[(size_t)(HH + k + kk) * HH + cc + 64 * j];
#pragma unroll
        for (int r = 0; r < 8; ++r) {
            float4 av = *(const float4*)&Ns[r0 + r][k];
            float a_[4] = {av.x, av.y, av.z, av.w};
#pragma unroll
            for (int kk = 0; kk < 4; ++kk)
#pragma unroll
                for (int j = 0; j < 4; ++j)
                    acc[r][j] += a_[kk] * w[kk][j];
        }
    }
#pragma unroll
    for (int r = 0; r < 8; ++r)
#pragma unroll
        for (int j = 0; j < 4; ++j) {
            float v = acc[r][j] + b1[cc + 64 * j];
            Fout[(size_t)(base + r0 + r) * HH + cc + 64 * j] = fmaxf(v, 0.f);
        }
}

// out[b,h] = sum_n feats[b,n,h]; deterministic (no atomics)
__global__ __launch_bounds__(256) void sum_kernel(const float* __restrict__ Fin,
                                                  float* __restrict__ out) {
    __shared__ float red[4][64];
    int b = blockIdx.x >> 2;
    int hg = blockIdx.x & 3;
    int lane = threadIdx.x & 63;
    int np = threadIdx.x >> 6;
    int c = hg * 64 + lane;
    float s = 0.f;
    for (int n = np * 128; n < np * 128 + 128; ++n)
        s += Fin[(size_t)(b * NN + n) * HH + c];
    red[np][lane] = s;
    __syncthreads();
    if (np == 0)
        out[b * HH + c] = (red[0][lane] + red[1][lane]) + (red[2][lane] + red[3][lane]);
}

extern "C" void kernel_launch(void* const* d_in, const int* in_sizes, int n_in,
                              void* d_out, int out_size, void* d_ws, size_t ws_size,
                              hipStream_t stream) {
    const float* input_bond    = (const float*)d_in[1];
    const int*   atom_graph    = (const int*)d_in[2];
    const int*   bond_graph    = (const int*)d_in[3];
    const int*   num_nbs       = (const int*)d_in[4];
    const float* atom_features = (const float*)d_in[5];
    const float* W2 = (const float*)d_in[6];
    const float* b2 = (const float*)d_in[7];
    const float* W1 = (const float*)d_in[8];
    const float* b1 = (const float*)d_in[9];
    float* out = (float*)d_out;
    float* ws  = (float*)d_ws;

    const size_t SZ = (size_t)ROWS * HH;   // 8,388,608 floats = 32 MB
    float* f0  = ws;            // feats ping
    float* f1  = ws + SZ;       // feats pong
    float* G   = ws + 2 * SZ;   // pre-activation atom messages
    float* Hb2 = ws + 3 * SZ;   // bond messages + b2 (loop-invariant)

    hb2_kernel<<<ROWS, 256, 0, stream>>>(input_bond, W2, b2, Hb2);

    const float* fin = atom_features;
    float* fout = f0;
    for (int d = 0; d < WLDEPTH; ++d) {
        gemmA_kernel<<<ROWS / TILE, 256, 0, stream>>>(fin, W2, G);
        fuseB_kernel<<<ROWS / TILE, 256, 0, stream>>>(fin, G, Hb2, atom_graph,
                                                      bond_graph, num_nbs, W1, b1, fout);
        fin = fout;
        fout = (d == 0) ? f1 : f0;
    }
    sum_kernel<<<BB * 4, 256, 0, stream>>>(fin, out);
}

// Round 3
// 586.191 us; speedup vs baseline: 1.5715x; 1.5715x over previous
//
#include <hip/hip_runtime.h>

// WL_DiffNet, bf16-MFMA version (round 2 + pk-staging bugfix: 320 entries
// must be written by 256 threads -> strided loop, not `if (tid<320)`).
// Factored algorithm (exact algebra, linearity commutes with gather):
//   Hb2 = input_bond @ W2[256:261] + b2        (fp32, once)
//   per depth:
//     G = feats(bf16) @ W2a(bf16)              (MFMA, fp32 out)
//     nei = sum_k relu(G[anei]+Hb2[bnei])*mask (fp32 gather, ILP-unrolled)
//     feats' = relu([feats|nei](bf16) @ W1(bf16) + b1)  (MFMA, bf16 out)
//   out[b,h] = sum_n feats[b,n,h]              (fp32)

#define BB 64
#define NN 512
#define MAXNB 10
#define HH 256
#define ROWS (BB*NN)   // 32768

typedef __attribute__((ext_vector_type(8))) short bf16x8;
typedef __attribute__((ext_vector_type(4))) float f32x4;
typedef unsigned short u16;
typedef unsigned int u32;

__device__ __forceinline__ u16 f2b(float f) {   // rne f32->bf16
    union { float f; u32 u; } v; v.f = f;
    u32 r = v.u + 0x7FFF + ((v.u >> 16) & 1);
    return (u16)(r >> 16);
}
__device__ __forceinline__ float b2f(u16 u) {
    union { u32 u; float f; } v; v.u = (u32)u << 16; return v.f;
}

// ---- one-time prep -------------------------------------------------------

__global__ __launch_bounds__(256) void castk(const float* __restrict__ in,
                                             u16* __restrict__ out) {
    int i = blockIdx.x * 256 + threadIdx.x;      // group of 4 elements
    float4 v = ((const float4*)in)[i];
    u32 a = f2b(v.x) | ((u32)f2b(v.y) << 16);
    u32 b = f2b(v.z) | ((u32)f2b(v.w) << 16);
    ((uint2*)out)[i] = make_uint2(a, b);
}

// WT[n*K + k] = bf16(W[k*N + n]); grid=K blocks, N=256 threads
__global__ __launch_bounds__(256) void twk(const float* __restrict__ W,
                                           u16* __restrict__ WT, int K) {
    int k = blockIdx.x, n = threadIdx.x;
    WT[(size_t)n * K + k] = f2b(W[(size_t)k * HH + n]);
}

__global__ __launch_bounds__(256) void hb2_kernel(const float* __restrict__ bond,
                                                  const float* __restrict__ W2,
                                                  const float* __restrict__ b2,
                                                  float* __restrict__ Hb2) {
    int row = blockIdx.x, c = threadIdx.x;
    float s = b2[c];
#pragma unroll
    for (int f = 0; f < 5; ++f)
        s += bond[row * 5 + f] * W2[(size_t)(HH + f) * HH + c];
    Hb2[(size_t)row * HH + c] = s;
}

// ---- gemmA: G[32r x 256] = Fbf @ W2aT^T (MFMA 16x16x32) ------------------
// LDS A tile XOR-swizzled: phys 16B slot = logical slot ^ (row&7)

__global__ __launch_bounds__(256) void gemmA_mfma(const u16* __restrict__ Fbf,
                                                  const u16* __restrict__ W2aT,
                                                  float* __restrict__ G) {
    __shared__ u16 As[32 * 256];   // 16KB
    int tid = threadIdx.x;
    int base = blockIdx.x * 32;
    const uint4* src = (const uint4*)(Fbf + (size_t)base * 256);
#pragma unroll
    for (int i = 0; i < 4; ++i) {
        int ci = tid + i * 256;
        int row = ci >> 5, s = ci & 31;
        ((uint4*)As)[row * 32 + (s ^ (row & 7))] = src[ci];
    }
    __syncthreads();

    int lane = tid & 63, wid = tid >> 6;
    int r0 = (wid & 1) * 16, c0 = (wid >> 1) * 128;
    int m = lane & 15, g = lane >> 4;
    int arow = r0 + m;
    f32x4 acc[8];
#pragma unroll
    for (int j = 0; j < 8; ++j) acc[j] = (f32x4){0.f, 0.f, 0.f, 0.f};

    for (int ks = 0; ks < 8; ++ks) {
        bf16x8 a = *(const bf16x8*)(As + arow * 256 + (((ks * 4 + g) ^ (arow & 7)) * 8));
#pragma unroll
        for (int j = 0; j < 8; ++j) {
            int n = c0 + j * 16 + m;
            bf16x8 b = *(const bf16x8*)(W2aT + (size_t)n * 256 + ks * 32 + g * 8);
            acc[j] = __builtin_amdgcn_mfma_f32_16x16x32_bf16(a, b, acc[j], 0, 0, 0);
        }
    }
#pragma unroll
    for (int j = 0; j < 8; ++j) {
        int col = c0 + j * 16 + m;
#pragma unroll
        for (int rr = 0; rr < 4; ++rr) {
            int row = base + r0 + g * 4 + rr;
            G[(size_t)row * 256 + col] = acc[j][rr];
        }
    }
}

// ---- fuseB: gather-aggregate (fp32) + [F|N]@W1 (MFMA) --------------------

__global__ __launch_bounds__(256) void fuseB_mfma(const u16* __restrict__ Fbf,
                                                  const float* __restrict__ G,
                                                  const float* __restrict__ Hb2,
                                                  const int* __restrict__ agr,
                                                  const int* __restrict__ bgr,
                                                  const int* __restrict__ nnb,
                                                  const u16* __restrict__ W1T,
                                                  const float* __restrict__ b1,
                                                  u16* __restrict__ Fout) {
    __shared__ u16 Fs[32 * 256];   // 16KB, swizzled
    __shared__ u16 Ns[32 * 256];   // 16KB, swizzled
    __shared__ int pk[320];        // packed an|bn<<9|valid<<18
    int tid = threadIdx.x;
    int base = blockIdx.x * 32;
    int brow = base & ~511;        // batch-pure blocks (32 | 512)

    const uint4* src = (const uint4*)(Fbf + (size_t)base * 256);
#pragma unroll
    for (int i = 0; i < 4; ++i) {
        int ci = tid + i * 256;
        int row = ci >> 5, s = ci & 31;
        ((uint4*)Fs)[row * 32 + (s ^ (row & 7))] = src[ci];
    }
    // 320 entries, 256 threads: strided loop (round-2 bug was `if (tid<320)`)
    for (int t = tid; t < 320; t += 256) {
        int r = t / 10, k = t % 10;
        int row = base + r;
        int an = agr[(row * MAXNB + k) * 2 + 1];
        int bn = bgr[(row * MAXNB + k) * 2 + 1];
        int valid = (k < nnb[row]) ? 1 : 0;
        pk[t] = an | (bn << 9) | (valid << 18);
    }
    __syncthreads();

    // phase 1: thread owns column c for all 32 rows; fixed-10 masked unroll for ILP
    int c = tid;
    const float* Gb = G + (size_t)brow * 256 + c;
    const float* Hb = Hb2 + (size_t)brow * 256 + c;
    for (int r = 0; r < 32; ++r) {
        float s = 0.f;
#pragma unroll
        for (int k = 0; k < MAXNB; ++k) {
            int p = pk[r * MAXNB + k];
            float ga = Gb[(p & 511) * 256];
            float hb = Hb[((p >> 9) & 511) * 256];
            float v = fmaxf(ga + hb, 0.f);
            s += (p & (1 << 18)) ? v : 0.f;
        }
        Ns[r * 256 + ((c >> 3) ^ (r & 7)) * 8 + (c & 7)] = f2b(s);
    }
    __syncthreads();

    // phase 2: feats' = relu([Fs|Ns] @ W1 + b1), K=512
    int lane = tid & 63, wid = tid >> 6;
    int r0 = (wid & 1) * 16, c0 = (wid >> 1) * 128;
    int m = lane & 15, g = lane >> 4;
    int arow = r0 + m;
    f32x4 acc[8];
#pragma unroll
    for (int j = 0; j < 8; ++j) acc[j] = (f32x4){0.f, 0.f, 0.f, 0.f};

    for (int ks = 0; ks < 8; ++ks) {
        bf16x8 a = *(const bf16x8*)(Fs + arow * 256 + (((ks * 4 + g) ^ (arow & 7)) * 8));
#pragma unroll
        for (int j = 0; j < 8; ++j) {
            int n = c0 + j * 16 + m;
            bf16x8 b = *(const bf16x8*)(W1T + (size_t)n * 512 + ks * 32 + g * 8);
            acc[j] = __builtin_amdgcn_mfma_f32_16x16x32_bf16(a, b, acc[j], 0, 0, 0);
        }
    }
    for (int ks = 0; ks < 8; ++ks) {
        bf16x8 a = *(const bf16x8*)(Ns + arow * 256 + (((ks * 4 + g) ^ (arow & 7)) * 8));
#pragma unroll
        for (int j = 0; j < 8; ++j) {
            int n = c0 + j * 16 + m;
            bf16x8 b = *(const bf16x8*)(W1T + (size_t)n * 512 + (ks + 8) * 32 + g * 8);
            acc[j] = __builtin_amdgcn_mfma_f32_16x16x32_bf16(a, b, acc[j], 0, 0, 0);
        }
    }
#pragma unroll
    for (int j = 0; j < 8; ++j) {
        int col = c0 + j * 16 + m;
        float bb = b1[col];
#pragma unroll
        for (int rr = 0; rr < 4; ++rr) {
            int row = base + r0 + g * 4 + rr;
            Fout[(size_t)row * 256 + col] = f2b(fmaxf(acc[j][rr] + bb, 0.f));
        }
    }
}

// ---- final sum over atoms (deterministic) --------------------------------

__global__ __launch_bounds__(256) void sum_bf16(const u16* __restrict__ F,
                                                float* __restrict__ out) {
    __shared__ float red[4][256];
    int b = blockIdx.x, tid = threadIdx.x;
    int cg = tid & 63, rg = tid >> 6;
    float s0 = 0, s1 = 0, s2 = 0, s3 = 0;
    const u16* Fb = F + (size_t)(b * NN + rg * 128) * 256 + cg * 4;
    for (int n = 0; n < 128; ++n) {
        ushort4 v = *(const ushort4*)(Fb + (size_t)n * 256);
        s0 += b2f(v.x); s1 += b2f(v.y); s2 += b2f(v.z); s3 += b2f(v.w);
    }
    red[rg][cg * 4 + 0] = s0; red[rg][cg * 4 + 1] = s1;
    red[rg][cg * 4 + 2] = s2; red[rg][cg * 4 + 3] = s3;
    __syncthreads();
    if (rg == 0) {
#pragma unroll
        for (int j = 0; j < 4; ++j) {
            int cc = cg * 4 + j;
            out[b * 256 + cc] = (red[0][cc] + red[1][cc]) + (red[2][cc] + red[3][cc]);
        }
    }
}

extern "C" void kernel_launch(void* const* d_in, const int* in_sizes, int n_in,
                              void* d_out, int out_size, void* d_ws, size_t ws_size,
                              hipStream_t stream) {
    const float* input_bond    = (const float*)d_in[1];
    const int*   atom_graph    = (const int*)d_in[2];
    const int*   bond_graph    = (const int*)d_in[3];
    const int*   num_nbs       = (const int*)d_in[4];
    const float* atom_features = (const float*)d_in[5];
    const float* W2 = (const float*)d_in[6];
    const float* b2 = (const float*)d_in[7];
    const float* W1 = (const float*)d_in[8];
    const float* b1 = (const float*)d_in[9];
    float* out = (float*)d_out;

    char* w = (char*)d_ws;
    u16*   f0   = (u16*)w;                                   // 16MB
    u16*   f1   = (u16*)(w + ((size_t)16 << 20));            // 16MB
    float* G    = (float*)(w + ((size_t)32 << 20));          // 32MB
    float* Hb2  = (float*)(w + ((size_t)64 << 20));          // 32MB
    u16*   W2aT = (u16*)(w + ((size_t)96 << 20));            // 128KB
    u16*   W1T  = (u16*)(w + ((size_t)96 << 20) + (256 << 10)); // 256KB

    castk<<<ROWS * HH / 1024, 256, 0, stream>>>(atom_features, f0);
    twk<<<256, 256, 0, stream>>>(W2, W2aT, 256);
    twk<<<512, 256, 0, stream>>>(W1, W1T, 512);
    hb2_kernel<<<ROWS, 256, 0, stream>>>(input_bond, W2, b2, Hb2);

    const u16* fin = f0;
    u16* fout = f1;
    for (int d = 0; d < 3; ++d) {
        gemmA_mfma<<<ROWS / 32, 256, 0, stream>>>(fin, W2aT, G);
        fuseB_mfma<<<ROWS / 32, 256, 0, stream>>>(fin, G, Hb2, atom_graph,
                                                  bond_graph, num_nbs, W1T, b1, fout);
        fin = fout;
        fout = (fout == f1) ? f0 : f1;
    }
    sum_bf16<<<BB, 256, 0, stream>>>(fin, out);
}

// Round 4
// 388.757 us; speedup vs baseline: 2.3696x; 1.5079x over previous
//
#include <hip/hip_runtime.h>

// WL_DiffNet bf16-MFMA, round 4: XCD-bijective swizzle (batch->XCD L2
// locality), G/Hb2 in bf16 (halved gather traffic, ~4MB/XCD working set),
// 4-col/thread uint2 gather.
//   Hb2 = bf16(input_bond @ W2[256:261] + b2)   (once)
//   per depth:
//     G = bf16(feats @ W2a)                     (MFMA)
//     nei = sum_k relu(G[anei]+Hb2[bnei])*mask  (fp32 acc gather)
//     feats' = relu([feats|nei] @ W1 + b1)      (MFMA, bf16 out)
//   out[b,h] = sum_n feats[b,n,h]

#define BB 64
#define NN 512
#define MAXNB 10
#define HH 256
#define ROWS (BB*NN)   // 32768

typedef __attribute__((ext_vector_type(8))) short bf16x8;
typedef __attribute__((ext_vector_type(4))) float f32x4;
typedef unsigned short u16;
typedef unsigned int u32;

__device__ __forceinline__ u16 f2b(float f) {   // rne f32->bf16
    union { float f; u32 u; } v; v.f = f;
    u32 r = v.u + 0x7FFF + ((v.u >> 16) & 1);
    return (u16)(r >> 16);
}
__device__ __forceinline__ float b2f(u32 u) {   // low 16 bits -> f32
    union { u32 u; float f; } v; v.u = u << 16; return v.f;
}

// XCD-bijective swizzle: hardware round-robins blockIdx across 8 XCDs;
// remap so XCD x owns contiguous tiles [x*nwg/8, (x+1)*nwg/8). nwg%8==0.
__device__ __forceinline__ int xcd_swz(int bid, int nwg) {
    return (bid & 7) * (nwg >> 3) + (bid >> 3);
}

// ---- one-time prep -------------------------------------------------------

__global__ __launch_bounds__(256) void castk(const float* __restrict__ in,
                                             u16* __restrict__ out) {
    int i = blockIdx.x * 256 + threadIdx.x;
    float4 v = ((const float4*)in)[i];
    u32 a = f2b(v.x) | ((u32)f2b(v.y) << 16);
    u32 b = f2b(v.z) | ((u32)f2b(v.w) << 16);
    ((uint2*)out)[i] = make_uint2(a, b);
}

__global__ __launch_bounds__(256) void twk(const float* __restrict__ W,
                                           u16* __restrict__ WT, int K) {
    int k = blockIdx.x, n = threadIdx.x;
    WT[(size_t)n * K + k] = f2b(W[(size_t)k * HH + n]);
}

__global__ __launch_bounds__(256) void hb2_kernel(const float* __restrict__ bond,
                                                  const float* __restrict__ W2,
                                                  const float* __restrict__ b2,
                                                  u16* __restrict__ Hb2) {
    int row = blockIdx.x, c = threadIdx.x;
    float s = b2[c];
#pragma unroll
    for (int f = 0; f < 5; ++f)
        s += bond[row * 5 + f] * W2[(size_t)(HH + f) * HH + c];
    Hb2[(size_t)row * HH + c] = f2b(s);
}

// ---- gemmA: G[32r x 256] = Fbf @ W2aT^T (MFMA 16x16x32), bf16 out --------

__global__ __launch_bounds__(256) void gemmA_mfma(const u16* __restrict__ Fbf,
                                                  const u16* __restrict__ W2aT,
                                                  u16* __restrict__ G) {
    __shared__ u16 As[32 * 256];   // 16KB, swizzled 16B slots
    int tid = threadIdx.x;
    int base = xcd_swz(blockIdx.x, gridDim.x) * 32;
    const uint4* src = (const uint4*)(Fbf + (size_t)base * 256);
#pragma unroll
    for (int i = 0; i < 4; ++i) {
        int ci = tid + i * 256;
        int row = ci >> 5, s = ci & 31;
        ((uint4*)As)[row * 32 + (s ^ (row & 7))] = src[ci];
    }
    __syncthreads();

    int lane = tid & 63, wid = tid >> 6;
    int r0 = (wid & 1) * 16, c0 = (wid >> 1) * 128;
    int m = lane & 15, g = lane >> 4;
    int arow = r0 + m;
    f32x4 acc[8];
#pragma unroll
    for (int j = 0; j < 8; ++j) acc[j] = (f32x4){0.f, 0.f, 0.f, 0.f};

    for (int ks = 0; ks < 8; ++ks) {
        bf16x8 a = *(const bf16x8*)(As + arow * 256 + (((ks * 4 + g) ^ (arow & 7)) * 8));
#pragma unroll
        for (int j = 0; j < 8; ++j) {
            int n = c0 + j * 16 + m;
            bf16x8 b = *(const bf16x8*)(W2aT + (size_t)n * 256 + ks * 32 + g * 8);
            acc[j] = __builtin_amdgcn_mfma_f32_16x16x32_bf16(a, b, acc[j], 0, 0, 0);
        }
    }
#pragma unroll
    for (int j = 0; j < 8; ++j) {
        int col = c0 + j * 16 + m;
#pragma unroll
        for (int rr = 0; rr < 4; ++rr) {
            int row = base + r0 + g * 4 + rr;
            G[(size_t)row * 256 + col] = f2b(acc[j][rr]);
        }
    }
}

// ---- fuseB: gather-aggregate (fp32 acc over bf16 G/Hb2) + [F|N]@W1 -------

__global__ __launch_bounds__(256) void fuseB_mfma(const u16* __restrict__ Fbf,
                                                  const u16* __restrict__ G,
                                                  const u16* __restrict__ Hb2,
                                                  const int* __restrict__ agr,
                                                  const int* __restrict__ bgr,
                                                  const int* __restrict__ nnb,
                                                  const u16* __restrict__ W1T,
                                                  const float* __restrict__ b1,
                                                  u16* __restrict__ Fout) {
    __shared__ u16 Fs[32 * 256];   // 16KB, swizzled
    __shared__ u16 Ns[32 * 256];   // 16KB, swizzled
    __shared__ int pk[320];        // packed an|bn<<9|valid<<18
    int tid = threadIdx.x;
    int base = xcd_swz(blockIdx.x, gridDim.x) * 32;
    int brow = base & ~511;        // batch row base (32 | 512)

    const uint4* src = (const uint4*)(Fbf + (size_t)base * 256);
#pragma unroll
    for (int i = 0; i < 4; ++i) {
        int ci = tid + i * 256;
        int row = ci >> 5, s = ci & 31;
        ((uint4*)Fs)[row * 32 + (s ^ (row & 7))] = src[ci];
    }
    for (int t = tid; t < 320; t += 256) {     // 320 entries, 256 threads
        int r = t / 10, k = t % 10;
        int row = base + r;
        int an = agr[(row * MAXNB + k) * 2 + 1];
        int bn = bgr[(row * MAXNB + k) * 2 + 1];
        int valid = (k < nnb[row]) ? 1 : 0;
        pk[t] = an | (bn << 9) | (valid << 18);
    }
    __syncthreads();

    // phase 1: thread owns 4 columns for 8 rows; uint2 = 4x bf16 per load
    {
        int q = tid >> 6;              // row quarter: rows [q*8, q*8+8)
        int c4 = (tid & 63) * 4;       // columns c4..c4+3
        const uint2* Gb = (const uint2*)(G + (size_t)brow * 256) + (c4 >> 2);
        const uint2* Hb = (const uint2*)(Hb2 + (size_t)brow * 256) + (c4 >> 2);
        for (int r = q * 8; r < q * 8 + 8; ++r) {
            float s0 = 0.f, s1 = 0.f, s2 = 0.f, s3 = 0.f;
#pragma unroll
            for (int k = 0; k < MAXNB; ++k) {
                int p = pk[r * MAXNB + k];
                uint2 ga = Gb[(size_t)(p & 511) * 64];
                uint2 hb = Hb[(size_t)((p >> 9) & 511) * 64];
                float v0 = fmaxf(b2f(ga.x & 0xffffu) + b2f(hb.x & 0xffffu), 0.f);
                float v1 = fmaxf(b2f(ga.x >> 16)     + b2f(hb.x >> 16),     0.f);
                float v2 = fmaxf(b2f(ga.y & 0xffffu) + b2f(hb.y & 0xffffu), 0.f);
                float v3 = fmaxf(b2f(ga.y >> 16)     + b2f(hb.y >> 16),     0.f);
                bool valid = (p & (1 << 18)) != 0;
                s0 += valid ? v0 : 0.f;
                s1 += valid ? v1 : 0.f;
                s2 += valid ? v2 : 0.f;
                s3 += valid ? v3 : 0.f;
            }
            u32 lo = f2b(s0) | ((u32)f2b(s1) << 16);
            u32 hi = f2b(s2) | ((u32)f2b(s3) << 16);
            *(uint2*)(Ns + r * 256 + (((c4 >> 3) ^ (r & 7)) * 8) + (c4 & 7)) =
                make_uint2(lo, hi);
        }
    }
    __syncthreads();

    // phase 2: feats' = relu([Fs|Ns] @ W1 + b1), K=512
    int lane = tid & 63, wid = tid >> 6;
    int r0 = (wid & 1) * 16, c0 = (wid >> 1) * 128;
    int m = lane & 15, g = lane >> 4;
    int arow = r0 + m;
    f32x4 acc[8];
#pragma unroll
    for (int j = 0; j < 8; ++j) acc[j] = (f32x4){0.f, 0.f, 0.f, 0.f};

    for (int ks = 0; ks < 8; ++ks) {
        bf16x8 a = *(const bf16x8*)(Fs + arow * 256 + (((ks * 4 + g) ^ (arow & 7)) * 8));
#pragma unroll
        for (int j = 0; j < 8; ++j) {
            int n = c0 + j * 16 + m;
            bf16x8 b = *(const bf16x8*)(W1T + (size_t)n * 512 + ks * 32 + g * 8);
            acc[j] = __builtin_amdgcn_mfma_f32_16x16x32_bf16(a, b, acc[j], 0, 0, 0);
        }
    }
    for (int ks = 0; ks < 8; ++ks) {
        bf16x8 a = *(const bf16x8*)(Ns + arow * 256 + (((ks * 4 + g) ^ (arow & 7)) * 8));
#pragma unroll
        for (int j = 0; j < 8; ++j) {
            int n = c0 + j * 16 + m;
            bf16x8 b = *(const bf16x8*)(W1T + (size_t)n * 512 + (ks + 8) * 32 + g * 8);
            acc[j] = __builtin_amdgcn_mfma_f32_16x16x32_bf16(a, b, acc[j], 0, 0, 0);
        }
    }
#pragma unroll
    for (int j = 0; j < 8; ++j) {
        int col = c0 + j * 16 + m;
        float bb = b1[col];
#pragma unroll
        for (int rr = 0; rr < 4; ++rr) {
            int row = base + r0 + g * 4 + rr;
            Fout[(size_t)row * 256 + col] = f2b(fmaxf(acc[j][rr] + bb, 0.f));
        }
    }
}

// ---- final sum over atoms (deterministic) --------------------------------

__global__ __launch_bounds__(256) void sum_bf16(const u16* __restrict__ F,
                                                float* __restrict__ out) {
    __shared__ float red[4][256];
    int b = blockIdx.x, tid = threadIdx.x;
    int cg = tid & 63, rg = tid >> 6;
    float s0 = 0, s1 = 0, s2 = 0, s3 = 0;
    const u16* Fb = F + (size_t)(b * NN + rg * 128) * 256 + cg * 4;
    for (int n = 0; n < 128; ++n) {
        ushort4 v = *(const ushort4*)(Fb + (size_t)n * 256);
        s0 += b2f(v.x); s1 += b2f(v.y); s2 += b2f(v.z); s3 += b2f(v.w);
    }
    red[rg][cg * 4 + 0] = s0; red[rg][cg * 4 + 1] = s1;
    red[rg][cg * 4 + 2] = s2; red[rg][cg * 4 + 3] = s3;
    __syncthreads();
    if (rg == 0) {
#pragma unroll
        for (int j = 0; j < 4; ++j) {
            int cc = cg * 4 + j;
            out[b * 256 + cc] = (red[0][cc] + red[1][cc]) + (red[2][cc] + red[3][cc]);
        }
    }
}

extern "C" void kernel_launch(void* const* d_in, const int* in_sizes, int n_in,
                              void* d_out, int out_size, void* d_ws, size_t ws_size,
                              hipStream_t stream) {
    const float* input_bond    = (const float*)d_in[1];
    const int*   atom_graph    = (const int*)d_in[2];
    const int*   bond_graph    = (const int*)d_in[3];
    const int*   num_nbs       = (const int*)d_in[4];
    const float* atom_features = (const float*)d_in[5];
    const float* W2 = (const float*)d_in[6];
    const float* b2 = (const float*)d_in[7];
    const float* W1 = (const float*)d_in[8];
    const float* b1 = (const float*)d_in[9];
    float* out = (float*)d_out;

    char* w = (char*)d_ws;
    u16*   f0   = (u16*)w;                                      // 16MB
    u16*   f1   = (u16*)(w + ((size_t)16 << 20));               // 16MB
    u16*   G    = (u16*)(w + ((size_t)32 << 20));               // 16MB
    u16*   Hb2  = (u16*)(w + ((size_t)48 << 20));               // 16MB
    u16*   W2aT = (u16*)(w + ((size_t)64 << 20));               // 128KB
    u16*   W1T  = (u16*)(w + ((size_t)64 << 20) + (256 << 10)); // 256KB

    castk<<<ROWS * HH / 1024, 256, 0, stream>>>(atom_features, f0);
    twk<<<256, 256, 0, stream>>>(W2, W2aT, 256);
    twk<<<512, 256, 0, stream>>>(W1, W1T, 512);
    hb2_kernel<<<ROWS, 256, 0, stream>>>(input_bond, W2, b2, Hb2);

    const u16* fin = f0;
    u16* fout = f1;
    for (int d = 0; d < 3; ++d) {
        gemmA_mfma<<<ROWS / 32, 256, 0, stream>>>(fin, W2aT, G);
        fuseB_mfma<<<ROWS / 32, 256, 0, stream>>>(fin, G, Hb2, atom_graph,
                                                  bond_graph, num_nbs, W1T, b1, fout);
        fin = fout;
        fout = (fout == f1) ? f0 : f1;
    }
    sum_bf16<<<BB, 256, 0, stream>>>(fin, out);
}